// Round 1
// baseline (137.819 us; speedup 1.0000x reference)
//
#include <hip/hip_runtime.h>

// LengthRegulator: b=16, t_x=1024, d=256, out_len=7168 (fixed by setup_inputs)
#define B       16
#define TX      1024
#define D       256
#define OUT_LEN 7168
#define TILE    16          // output rows per block in expand kernel

// ---------------------------------------------------------------------------
// Kernel 1: per-batch inclusive scan of repeat_count -> cum (int, in d_ws),
// and lengths (as float) into the tail of d_out.
// One block per batch, 256 threads, 4 elements per thread.
// ---------------------------------------------------------------------------
__global__ __launch_bounds__(256) void lr_scan_kernel(
        const int* __restrict__ rc,      // (B, TX) int32
        int* __restrict__ cum,           // (B, TX) int32 out (workspace)
        float* __restrict__ len_out)     // d_out + B*OUT_LEN*D, B floats
{
    __shared__ int part[256];
    const int b = blockIdx.x;
    const int t = threadIdx.x;

    const int4* rc4 = (const int4*)(rc + b * TX);
    int4 v = rc4[t];
    const int s0 = v.x;
    const int s1 = s0 + v.y;
    const int s2 = s1 + v.z;
    const int s3 = s2 + v.w;

    part[t] = s3;
    __syncthreads();

    // Hillis-Steele inclusive scan over the 256 per-thread sums
    #pragma unroll
    for (int off = 1; off < 256; off <<= 1) {
        int tmp = (t >= off) ? part[t - off] : 0;
        __syncthreads();
        part[t] += tmp;
        __syncthreads();
    }

    const int excl = part[t] - s3;   // exclusive prefix of this thread's group
    int4 c;
    c.x = excl + s0;
    c.y = excl + s1;
    c.z = excl + s2;
    c.w = excl + s3;
    ((int4*)(cum + b * TX))[t] = c;

    if (t == 255) {
        len_out[b] = (float)part[255];   // lengths[b] = cum[b, TX-1]
    }
}

// ---------------------------------------------------------------------------
// Kernel 2: expand. Each block handles TILE consecutive output rows of one
// batch. cum row cached in LDS; one wave (64 lanes) per output row does a
// branchless lower-bound then a coalesced float4 row copy.
// out[b, j, :] = x[b, i, :] where cum[i-1] <= j < cum[i]; zero if j >= total.
// ---------------------------------------------------------------------------
__global__ __launch_bounds__(256) void lr_expand_kernel(
        const float* __restrict__ x,     // (B, TX, D)
        const int* __restrict__ cum,     // (B, TX)
        float* __restrict__ out)         // (B, OUT_LEN, D)
{
    __shared__ int scum[TX];

    const int blocks_per_batch = OUT_LEN / TILE;   // 448
    const int b    = blockIdx.x / blocks_per_batch;
    const int row0 = (blockIdx.x % blocks_per_batch) * TILE;
    const int t    = threadIdx.x;

    // load cum[b, 0:TX] into LDS (256 threads x int4)
    ((int4*)scum)[t] = ((const int4*)(cum + b * TX))[t];
    __syncthreads();

    const int total = scum[TX - 1];
    const int lane4 = t & 63;   // float4 slot within the row (64 * 16B = 1KB)
    const int sub   = t >> 6;   // which of 4 concurrent rows this wave handles

    const float4* x4   = (const float4*)(x + (size_t)b * TX * D);
    float4*       out4 = (float4*)(out + (size_t)b * OUT_LEN * D);

    #pragma unroll
    for (int r = sub; r < TILE; r += 4) {
        const int j = row0 + r;
        float4 val = make_float4(0.f, 0.f, 0.f, 0.f);
        if (j < total) {
            // branchless lower-bound: i = count of cum[k] <= j
            // = first index with cum[i] > j  (TX is a power of two)
            int i = 0;
            #pragma unroll
            for (int step = TX / 2; step > 0; step >>= 1) {
                if (scum[i + step - 1] <= j) i += step;
            }
            val = x4[(size_t)i * (D / 4) + lane4];
        }
        out4[(size_t)j * (D / 4) + lane4] = val;
    }
}

extern "C" void kernel_launch(void* const* d_in, const int* in_sizes, int n_in,
                              void* d_out, int out_size, void* d_ws, size_t ws_size,
                              hipStream_t stream) {
    const float* x  = (const float*)d_in[0];
    const int*   rc = (const int*)d_in[1];     // repeat_count (int32 on device)
    float* out = (float*)d_out;
    float* len_out = out + (size_t)B * OUT_LEN * D;   // lengths chunk (B floats)
    int* cum = (int*)d_ws;                            // (B, TX) int32 scratch

    lr_scan_kernel<<<B, 256, 0, stream>>>(rc, cum, len_out);

    const int grid = B * (OUT_LEN / TILE);            // 7168 blocks
    lr_expand_kernel<<<grid, 256, 0, stream>>>(x, cum, out);
}